// Round 1
// baseline (605.007 us; speedup 1.0000x reference)
//
#include <hip/hip_runtime.h>

#define C_CH 16
#define Hdim 128
#define Wdim 128
#define HWdim 16384
#define Bdim 2
#define PAIR_ELEMS (Bdim * C_CH * HWdim)   // 524288 floats per feature map

// ---------------------------------------------------------------------------
// Prep: transpose memories into two layouts:
//   memT[d][m]            (for sim conv: contiguous in m for s_load)
//   memR[m][u][v][c]      (kernel-flipped, contiguous in c for read conv)
// ---------------------------------------------------------------------------
struct PrepDesc {
  const float* mem;
  float* memT;
  float* memR;
  int M, D, P;
};
struct PrepArgs { PrepDesc d[6]; };

__global__ __launch_bounds__(256) void k_prep(PrepArgs a) {
  PrepDesc de = a.d[blockIdx.y];
  int n = de.M * de.D;
  int idx = blockIdx.x * 256 + threadIdx.x;
  if (idx >= n) return;
  int m = idx / de.D;
  int d = idx - m * de.D;
  float v = de.mem[idx];
  de.memT[d * de.M + m] = v;
  int pp = de.P * de.P;
  int c = d / pp;
  int r = d - c * pp;
  int i = r / de.P;
  int j = r - i * de.P;
  de.memR[((m * de.P + (de.P - 1 - i)) * de.P + (de.P - 1 - j)) * C_CH + c] = v;
}

// ---------------------------------------------------------------------------
// Sim conv + per-pixel softmax -> att[b][m][y][x]
// 8x8 pixel tile / block; 4 waves split the M memories (MC = M/4 each).
// ---------------------------------------------------------------------------
template<int P, int M>
__global__ __launch_bounds__(256) void k_sim(
    const float* __restrict__ x, const float* __restrict__ memT,
    const float* __restrict__ temp, float* __restrict__ att)
{
  constexpr int PAD = P / 2;
  constexpr int TH = 8 + P - 1;      // tile + halo span (even)
  constexpr int SR = TH + 1;         // odd row stride: no LDS bank hot-spots
  constexpr int D = C_CH * P * P;
  constexpr int MC = M / 4;

  __shared__ float xt[C_CH][TH][SR];
  __shared__ float red[4][64];

  const int tid  = threadIdx.x;
  const int wave = tid >> 6;
  const int lane = tid & 63;
  const int px = lane & 7, py = lane >> 3;
  const int x0 = blockIdx.x * 8, y0 = blockIdx.y * 8;
  const int b  = blockIdx.z;

  // stage input tile (+halo, zero padded) to LDS
  for (int c = 0; c < C_CH; ++c) {
    for (int t = tid; t < TH * TH; t += 256) {
      int ly = t / TH, lx = t - ly * TH;
      int gy = y0 - PAD + ly, gx = x0 - PAD + lx;
      float v = 0.f;
      if (gy >= 0 && gy < Hdim && gx >= 0 && gx < Wdim)
        v = x[((b * C_CH + c) * Hdim + gy) * Wdim + gx];
      xt[c][ly][lx] = v;
    }
  }
  __syncthreads();

  const int m0 = __builtin_amdgcn_readfirstlane(wave * MC);
  float acc[MC];
#pragma unroll
  for (int mm = 0; mm < MC; ++mm) acc[mm] = 0.f;

  const float* wp = memT + m0;
  for (int c = 0; c < C_CH; ++c) {
    for (int i = 0; i < P; ++i) {
#pragma unroll
      for (int j = 0; j < P; ++j) {
        float val = xt[c][py + i][px + j];
        const float* wr = wp + (size_t)(((c * P + i) * P + j)) * M;
#pragma unroll
        for (int mm = 0; mm < MC; ++mm) acc[mm] = fmaf(val, wr[mm], acc[mm]);
      }
    }
  }

  const float s = temp[0] / sqrtf((float)D);
  float pm = -3.4e38f;
#pragma unroll
  for (int mm = 0; mm < MC; ++mm) { acc[mm] *= s; pm = fmaxf(pm, acc[mm]); }
  red[wave][lane] = pm;
  __syncthreads();
  float gm = fmaxf(fmaxf(red[0][lane], red[1][lane]),
                   fmaxf(red[2][lane], red[3][lane]));
  __syncthreads();
  float ps = 0.f;
#pragma unroll
  for (int mm = 0; mm < MC; ++mm) { acc[mm] = __expf(acc[mm] - gm); ps += acc[mm]; }
  red[wave][lane] = ps;
  __syncthreads();
  float tot = red[0][lane] + red[1][lane] + red[2][lane] + red[3][lane];
  float inv = 1.f / tot;

  const int gy = y0 + py, gx = x0 + px;
#pragma unroll
  for (int mm = 0; mm < MC; ++mm)
    att[((size_t)(b * M + m0 + mm) * Hdim + gy) * Wdim + gx] = acc[mm] * inv;
}

// ---------------------------------------------------------------------------
// Read conv (= fold of att@mem) + divide by analytic overlap count -> feat
// ---------------------------------------------------------------------------
template<int P, int M>
__global__ __launch_bounds__(256) void k_read(
    const float* __restrict__ att, const float* __restrict__ memR,
    float* __restrict__ feat)
{
  constexpr int PAD = P / 2;
  constexpr int TH = 8 + P - 1;
  constexpr int SR = TH + 1;
  constexpr int MC = M / 4;
  constexpr int SUB = (MC >= 4) ? 4 : MC;
  constexpr int NSUB = MC / SUB;

  __shared__ float at[4][SUB][TH][SR];
  __shared__ float red[4][64][C_CH + 1];   // +1: avoid 32-way bank conflict

  const int tid  = threadIdx.x;
  const int wave = tid >> 6;
  const int lane = tid & 63;
  const int px = lane & 7, py = lane >> 3;
  const int x0 = blockIdx.x * 8, y0 = blockIdx.y * 8;
  const int b  = blockIdx.z;

  const int m0 = __builtin_amdgcn_readfirstlane(wave * MC);

  float acc[C_CH];
#pragma unroll
  for (int c = 0; c < C_CH; ++c) acc[c] = 0.f;

  for (int sref = 0; sref < NSUB; ++sref) {
    // this wave stages its SUB att channels (+halo, zero pad) into its LDS slot
    for (int t = lane; t < SUB * TH * TH; t += 64) {
      int ms = t / (TH * TH);
      int r  = t - ms * (TH * TH);
      int ly = r / TH, lx = r - ly * TH;
      int gy = y0 - PAD + ly, gx = x0 - PAD + lx;
      float v = 0.f;
      if (gy >= 0 && gy < Hdim && gx >= 0 && gx < Wdim)
        v = att[((size_t)(b * M + m0 + sref * SUB + ms) * Hdim + gy) * Wdim + gx];
      at[wave][ms][ly][lx] = v;
    }
    __syncthreads();
    for (int ms = 0; ms < SUB; ++ms) {
      const int m = m0 + sref * SUB + ms;
      for (int u = 0; u < P; ++u) {
#pragma unroll
        for (int v2 = 0; v2 < P; ++v2) {
          float val = at[wave][ms][py + u][px + v2];
          const float* wr = memR + (size_t)(((m * P + u) * P + v2)) * C_CH;
#pragma unroll
          for (int c = 0; c < C_CH; ++c) acc[c] = fmaf(val, wr[c], acc[c]);
        }
      }
    }
    __syncthreads();
  }

#pragma unroll
  for (int c = 0; c < C_CH; ++c) red[wave][lane][c] = acc[c];
  __syncthreads();

  const int gy = y0 + py, gx = x0 + px;
  int cy = min(P - 1, gy + PAD) - max(0, gy + PAD - Hdim + 1) + 1;
  int cx = min(P - 1, gx + PAD) - max(0, gx + PAD - Wdim + 1) + 1;
  float dv = (float)(cy * cx) + 1e-8f;
#pragma unroll
  for (int cc = 0; cc < 4; ++cc) {
    int c = wave * 4 + cc;
    float sum = red[0][lane][c] + red[1][lane][c] + red[2][lane][c] + red[3][lane][c];
    feat[((size_t)(b * C_CH + c) * Hdim + gy) * Wdim + gx] = sum / dv;
  }
}

// ---------------------------------------------------------------------------
// Fusion: pooled mean of summed scales -> MLP -> softmax over scales -> mix
// ---------------------------------------------------------------------------
__global__ __launch_bounds__(256) void k_pool(const float* __restrict__ feats,
                                              float* __restrict__ pooled)
{
  __shared__ float r[256];
  int bid = blockIdx.x;          // br*32 + b*16 + c
  int br = bid >> 5;
  int bc = bid & 31;
  const float* f0 = feats + (size_t)(br * 3 + 0) * PAIR_ELEMS + (size_t)bc * HWdim;
  const float* f1 = feats + (size_t)(br * 3 + 1) * PAIR_ELEMS + (size_t)bc * HWdim;
  const float* f2 = feats + (size_t)(br * 3 + 2) * PAIR_ELEMS + (size_t)bc * HWdim;
  float s = 0.f;
  for (int t = threadIdx.x; t < HWdim; t += 256)
    s += f0[t] + f1[t] + f2[t];
  r[threadIdx.x] = s;
  __syncthreads();
  for (int off = 128; off > 0; off >>= 1) {
    if ((int)threadIdx.x < off) r[threadIdx.x] += r[threadIdx.x + off];
    __syncthreads();
  }
  if (threadIdx.x == 0) pooled[bid] = r[0] * (1.0f / (float)HWdim);
}

__global__ __launch_bounds__(128) void k_mlp(
    const float* __restrict__ pooled,
    const float* __restrict__ w1b, const float* __restrict__ b1b,
    const float* __restrict__ w2b, const float* __restrict__ b2b,
    const float* __restrict__ w1t, const float* __restrict__ b1t,
    const float* __restrict__ w2t, const float* __restrict__ b2t,
    float* __restrict__ wt)
{
  __shared__ float hdn[Bdim][4];
  __shared__ float lg[Bdim][48];
  int t = threadIdx.x;
  for (int br = 0; br < 2; ++br) {
    const float* w1 = br ? w1t : w1b;
    const float* b1 = br ? b1t : b1b;
    const float* w2 = br ? w2t : w2b;
    const float* b2 = br ? b2t : b2b;
    if (t < 8) {
      int b = t >> 2, h = t & 3;
      float s = b1[h];
      for (int c = 0; c < C_CH; ++c) s += pooled[br * 32 + b * 16 + c] * w1[h * 16 + c];
      hdn[b][h] = fmaxf(s, 0.f);
    }
    __syncthreads();
    if (t < 96) {
      int b = t / 48, j = t - b * 48;
      float s = b2[j];
      for (int h = 0; h < 4; ++h) s += hdn[b][h] * w2[j * 4 + h];
      lg[b][j] = s;
    }
    __syncthreads();
    if (t < 32) {
      int b = t >> 4, c = t & 15;
      float l0 = lg[b][c], l1 = lg[b][16 + c], l2 = lg[b][32 + c];
      float m = fmaxf(l0, fmaxf(l1, l2));
      float e0 = __expf(l0 - m), e1 = __expf(l1 - m), e2 = __expf(l2 - m);
      float inv = 1.f / (e0 + e1 + e2);
      wt[((br * 2 + b) * 3 + 0) * 16 + c] = e0 * inv;
      wt[((br * 2 + b) * 3 + 1) * 16 + c] = e1 * inv;
      wt[((br * 2 + b) * 3 + 2) * 16 + c] = e2 * inv;
    }
    __syncthreads();
  }
}

__global__ __launch_bounds__(256) void k_out(const float* __restrict__ feats,
                                             const float* __restrict__ wt,
                                             float* __restrict__ out)
{
  int idx = blockIdx.x * 256 + threadIdx.x;      // 0 .. 2*PAIR_ELEMS-1
  int br  = idx >> 19;                           // PAIR_ELEMS == 2^19
  int rem = idx & ((1 << 19) - 1);
  int bc  = rem >> 14;
  int b = bc >> 4, c = bc & 15;
  const float* fb = feats + (size_t)br * 3 * PAIR_ELEMS + rem;
  float w0 = wt[((br * 2 + b) * 3 + 0) * 16 + c];
  float w1 = wt[((br * 2 + b) * 3 + 1) * 16 + c];
  float w2 = wt[((br * 2 + b) * 3 + 2) * 16 + c];
  out[idx] = w0 * fb[0] + w1 * fb[PAIR_ELEMS] + w2 * fb[2 * PAIR_ELEMS];
}

// ---------------------------------------------------------------------------
extern "C" void kernel_launch(void* const* d_in, const int* in_sizes, int n_in,
                              void* d_out, int out_size, void* d_ws, size_t ws_size,
                              hipStream_t stream)
{
  const float* bg = (const float*)d_in[0];
  const float* tg = (const float*)d_in[1];
  const float* bg_mem[3]  = {(const float*)d_in[2],  (const float*)d_in[6],  (const float*)d_in[10]};
  const float* tg_mem[3]  = {(const float*)d_in[3],  (const float*)d_in[7],  (const float*)d_in[11]};
  const float* bg_temp[3] = {(const float*)d_in[4],  (const float*)d_in[8],  (const float*)d_in[12]};
  const float* tg_temp[3] = {(const float*)d_in[5],  (const float*)d_in[9],  (const float*)d_in[13]};
  const float* bg_fc1_w = (const float*)d_in[14];
  const float* bg_fc1_b = (const float*)d_in[15];
  const float* bg_fc2_w = (const float*)d_in[16];
  const float* bg_fc2_b = (const float*)d_in[17];
  const float* tg_fc1_w = (const float*)d_in[18];
  const float* tg_fc1_b = (const float*)d_in[19];
  const float* tg_fc2_w = (const float*)d_in[20];
  const float* tg_fc2_b = (const float*)d_in[21];

  float* ws     = (float*)d_ws;
  float* att    = ws;                          // 2*64*16384 = 2097152 floats
  float* feats  = att + 2097152;               // 6 * 524288
  float* memT   = feats + 6 * (size_t)PAIR_ELEMS;  // 95616
  float* memR   = memT + 95616;                // 95616
  float* pooled = memR + 95616;                // 64
  float* wt     = pooled + 64;                 // 192

  const int   Ms[6] = {64, 64, 64, 8, 8, 8};
  const int   Ps[6] = {3, 5, 7, 3, 5, 7};
  const float* mems[6] = {bg_mem[0], bg_mem[1], bg_mem[2], tg_mem[0], tg_mem[1], tg_mem[2]};
  float* memTs[6]; float* memRs[6];
  PrepArgs pa;
  size_t off = 0;
  for (int k = 0; k < 6; ++k) {
    int D = C_CH * Ps[k] * Ps[k];
    memTs[k] = memT + off;
    memRs[k] = memR + off;
    pa.d[k] = {mems[k], memTs[k], memRs[k], Ms[k], D, Ps[k]};
    off += (size_t)Ms[k] * D;
  }
  k_prep<<<dim3(196, 6), 256, 0, stream>>>(pa);

  dim3 g(Wdim / 8, Hdim / 8, Bdim), blk(256);
  // bg branch (M=64)
  k_sim<3, 64><<<g, blk, 0, stream>>>(bg, memTs[0], bg_temp[0], att);
  k_read<3, 64><<<g, blk, 0, stream>>>(att, memRs[0], feats + 0 * (size_t)PAIR_ELEMS);
  k_sim<5, 64><<<g, blk, 0, stream>>>(bg, memTs[1], bg_temp[1], att);
  k_read<5, 64><<<g, blk, 0, stream>>>(att, memRs[1], feats + 1 * (size_t)PAIR_ELEMS);
  k_sim<7, 64><<<g, blk, 0, stream>>>(bg, memTs[2], bg_temp[2], att);
  k_read<7, 64><<<g, blk, 0, stream>>>(att, memRs[2], feats + 2 * (size_t)PAIR_ELEMS);
  // tg branch (M=8)
  k_sim<3, 8><<<g, blk, 0, stream>>>(tg, memTs[3], tg_temp[0], att);
  k_read<3, 8><<<g, blk, 0, stream>>>(att, memRs[3], feats + 3 * (size_t)PAIR_ELEMS);
  k_sim<5, 8><<<g, blk, 0, stream>>>(tg, memTs[4], tg_temp[1], att);
  k_read<5, 8><<<g, blk, 0, stream>>>(att, memRs[4], feats + 4 * (size_t)PAIR_ELEMS);
  k_sim<7, 8><<<g, blk, 0, stream>>>(tg, memTs[5], tg_temp[2], att);
  k_read<7, 8><<<g, blk, 0, stream>>>(att, memRs[5], feats + 5 * (size_t)PAIR_ELEMS);

  k_pool<<<64, 256, 0, stream>>>(feats, pooled);
  k_mlp<<<1, 128, 0, stream>>>(pooled, bg_fc1_w, bg_fc1_b, bg_fc2_w, bg_fc2_b,
                               tg_fc1_w, tg_fc1_b, tg_fc2_w, tg_fc2_b, wt);
  k_out<<<(2 * PAIR_ELEMS) / 256, 256, 0, stream>>>(feats, wt, (float*)d_out);
}

// Round 2
// 475.574 us; speedup vs baseline: 1.2722x; 1.2722x over previous
//
#include <hip/hip_runtime.h>

#define C_CH 16
#define Hdim 128
#define Wdim 128
#define HWdim 16384
#define Bdim 2
#define PAIR_ELEMS (Bdim * C_CH * HWdim)   // 524288 floats per feature map

__device__ __forceinline__ void gadd(float* p, float v) {
  __hip_atomic_fetch_add(p, v, __ATOMIC_RELAXED, __HIP_MEMORY_SCOPE_AGENT);
}

// ---------------------------------------------------------------------------
// Prep: memT[d][m] = mem * temp/sqrt(D)   (sim conv weights, m-contiguous)
//       memR[m][u][v][c]                  (kernel-flipped, c-contiguous)
// ---------------------------------------------------------------------------
struct PrepDesc {
  const float* mem;
  const float* temp;
  float* memT;
  float* memR;
  int M, D, P;
};
struct PrepArgs { PrepDesc d[6]; };

__global__ __launch_bounds__(256) void k_prep(PrepArgs a) {
  PrepDesc de = a.d[blockIdx.y];
  int n = de.M * de.D;
  int idx = blockIdx.x * 256 + threadIdx.x;
  if (idx >= n) return;
  int m = idx / de.D;
  int d = idx - m * de.D;
  float v = de.mem[idx];
  float sc = de.temp[0] / sqrtf((float)de.D);
  de.memT[d * de.M + m] = v * sc;
  int pp = de.P * de.P;
  int c = d / pp;
  int r = d - c * pp;
  int i = r / de.P;
  int j = r - i * de.P;
  de.memR[((m * de.P + (de.P - 1 - i)) * de.P + (de.P - 1 - j)) * C_CH + c] = v;
}

// ---------------------------------------------------------------------------
// Sim conv + per-pixel softmax -> att[b][m][y][x]
// 8x8 pixel tile / block, 8 waves split the M memories. bg+tg in one dispatch.
// ---------------------------------------------------------------------------
template<int P, int M, int MC>
__device__ __forceinline__ void sim_core(
    const float* __restrict__ xt, float* __restrict__ red,
    const float* __restrict__ memT, float* __restrict__ att,
    int b, int wv, int lane, int x0, int y0)
{
  constexpr int TH = 8 + P - 1, SR = TH + 1;
  const int px = lane & 7, py = lane >> 3;
  const int m0 = wv * MC;
  float acc[MC];
#pragma unroll
  for (int mm = 0; mm < MC; ++mm) acc[mm] = 0.f;

  for (int c = 0; c < C_CH; ++c) {
#pragma unroll
    for (int i = 0; i < P; ++i) {
#pragma unroll
      for (int j = 0; j < P; ++j) {
        float val = xt[(c * TH + py + i) * SR + (px + j)];
        const float* wr = memT + (size_t)(((c * P + i) * P + j)) * M + m0;
#pragma unroll
        for (int mm = 0; mm < MC; ++mm) acc[mm] = fmaf(val, wr[mm], acc[mm]);
      }
    }
  }

  float pm = acc[0];
#pragma unroll
  for (int mm = 1; mm < MC; ++mm) pm = fmaxf(pm, acc[mm]);
  red[wv * 64 + lane] = pm;
  __syncthreads();
  float gm = red[lane];
#pragma unroll
  for (int w = 1; w < 8; ++w) gm = fmaxf(gm, red[w * 64 + lane]);
  __syncthreads();
  float ps = 0.f;
#pragma unroll
  for (int mm = 0; mm < MC; ++mm) { acc[mm] = __expf(acc[mm] - gm); ps += acc[mm]; }
  red[wv * 64 + lane] = ps;
  __syncthreads();
  float tot = 0.f;
#pragma unroll
  for (int w = 0; w < 8; ++w) tot += red[w * 64 + lane];
  float inv = 1.f / tot;

  const int gy = y0 + py, gx = x0 + px;
#pragma unroll
  for (int mm = 0; mm < MC; ++mm)
    att[((size_t)(b * M + m0 + mm) * Hdim + gy) * Wdim + gx] = acc[mm] * inv;
}

template<int P>
__global__ __launch_bounds__(512, 8) void k_sim(
    const float* __restrict__ xbg, const float* __restrict__ xtg,
    const float* __restrict__ memTbg, const float* __restrict__ memTtg,
    float* __restrict__ attbg, float* __restrict__ atttg)
{
  constexpr int PAD = P / 2, TH = 8 + P - 1, SR = TH + 1;
  __shared__ float xt[C_CH * TH * SR];
  __shared__ float red[8 * 64];

  const int tid = threadIdx.x;
  const int wv = __builtin_amdgcn_readfirstlane(tid >> 6);
  const int lane = tid & 63;
  const int x0 = blockIdx.x * 8, y0 = blockIdx.y * 8;
  const int z = blockIdx.z;
  const bool isbg = z < 2;
  const int b = z & 1;
  const float* x = isbg ? xbg : xtg;

  for (int t = tid; t < C_CH * TH * TH; t += 512) {
    int c = t / (TH * TH);
    int r = t - c * (TH * TH);
    int ly = r / TH, lx = r - ly * TH;
    int gy = y0 - PAD + ly, gx = x0 - PAD + lx;
    float v = 0.f;
    if (gy >= 0 && gy < Hdim && gx >= 0 && gx < Wdim)
      v = x[((b * C_CH + c) * Hdim + gy) * Wdim + gx];
    xt[(c * TH + ly) * SR + lx] = v;
  }
  __syncthreads();

  if (isbg) sim_core<P, 64, 8>(xt, red, memTbg, attbg, b, wv, lane, x0, y0);
  else      sim_core<P, 8, 1>(xt, red, memTtg, atttg, b, wv, lane, x0, y0);
}

// ---------------------------------------------------------------------------
// Read conv (fold of att@mem) with M chunked over gridDim.z; partial results
// pre-divided by analytic overlap count and atomically added into feat.
// ---------------------------------------------------------------------------
template<int P, int M, int MB, int MC>
__device__ __forceinline__ void read_core(
    float* __restrict__ at, float* __restrict__ sum,
    const float* __restrict__ att, const float* __restrict__ memR,
    float* __restrict__ feat, int b, int mbase,
    int tid, int wv, int lane, int x0, int y0)
{
  constexpr int PAD = P / 2, TH = 8 + P - 1, SR = TH + 1;

  for (int t = tid; t < 64 * 17; t += 256) sum[t] = 0.f;
  for (int t = tid; t < MB * TH * TH; t += 256) {
    int ml = t / (TH * TH);
    int r = t - ml * (TH * TH);
    int ly = r / TH, lx = r - ly * TH;
    int gy = y0 - PAD + ly, gx = x0 - PAD + lx;
    float v = 0.f;
    if (gy >= 0 && gy < Hdim && gx >= 0 && gx < Wdim)
      v = att[((size_t)(b * M + mbase + ml) * Hdim + gy) * Wdim + gx];
    at[(ml * TH + ly) * SR + lx] = v;
  }
  __syncthreads();

  const int px = lane & 7, py = lane >> 3;
  float acc[C_CH];
#pragma unroll
  for (int c = 0; c < C_CH; ++c) acc[c] = 0.f;

  const int ml0 = wv * MC;
  for (int ml = 0; ml < MC; ++ml) {
    const int m = mbase + ml0 + ml;
    const float* atm = at + (ml0 + ml) * TH * SR;
#pragma unroll
    for (int u = 0; u < P; ++u) {
#pragma unroll
      for (int v2 = 0; v2 < P; ++v2) {
        float val = atm[(py + u) * SR + (px + v2)];
        const float* wr = memR + (size_t)((m * P + u) * P + v2) * C_CH;
#pragma unroll
        for (int c = 0; c < C_CH; ++c) acc[c] = fmaf(val, wr[c], acc[c]);
      }
    }
  }

#pragma unroll
  for (int c = 0; c < C_CH; ++c) atomicAdd(&sum[lane * 17 + c], acc[c]);
  __syncthreads();

  const int gy = y0 + py, gx = x0 + px;
  int cy = min(P - 1, gy + PAD) - max(0, gy + PAD - (Hdim - 1)) + 1;
  int cx = min(P - 1, gx + PAD) - max(0, gx + PAD - (Wdim - 1)) + 1;
  float inv = 1.f / ((float)(cy * cx) + 1e-8f);
#pragma unroll
  for (int cc = 0; cc < 4; ++cc) {
    int c = wv * 4 + cc;
    float v = sum[lane * 17 + c] * inv;
    gadd(&feat[((size_t)(b * C_CH + c) * Hdim + gy) * Wdim + gx], v);
  }
}

template<int P>
__global__ __launch_bounds__(256, 8) void k_read(
    const float* __restrict__ attbg, const float* __restrict__ atttg,
    const float* __restrict__ memRbg, const float* __restrict__ memRtg,
    float* __restrict__ featbg, float* __restrict__ feattg)
{
  constexpr int TH = 8 + P - 1, SR = TH + 1;
  __shared__ float at[C_CH * TH * SR];   // sized for bg (16 m-channels)
  __shared__ float sum[64 * 17];

  const int tid = threadIdx.x;
  const int wv = __builtin_amdgcn_readfirstlane(tid >> 6);
  const int lane = tid & 63;
  const int x0 = blockIdx.x * 8, y0 = blockIdx.y * 8;
  const int z = blockIdx.z;

  if (z < 8) {   // bg: 4 m-chunks of 16
    read_core<P, 64, 16, 4>(at, sum, attbg, memRbg, featbg,
                            z >> 2, (z & 3) * 16, tid, wv, lane, x0, y0);
  } else {       // tg: one chunk of 8
    read_core<P, 8, 8, 2>(at, sum, atttg, memRtg, feattg,
                          z - 8, 0, tid, wv, lane, x0, y0);
  }
}

// ---------------------------------------------------------------------------
// Fusion
// ---------------------------------------------------------------------------
__global__ __launch_bounds__(256) void k_pool(const float* __restrict__ feats,
                                              float* __restrict__ pooled)
{
  __shared__ float r[256];
  int bid = blockIdx.x;          // br*32 + b*16 + c
  int chunk = blockIdx.y;        // quarter of HW
  int br = bid >> 5;
  int bc = bid & 31;
  const float* base = feats + (size_t)br * 3 * PAIR_ELEMS + (size_t)bc * HWdim
                      + chunk * 4096;
  float s = 0.f;
  for (int t = threadIdx.x; t < 4096; t += 256)
    s += base[t] + base[t + PAIR_ELEMS] + base[t + 2 * PAIR_ELEMS];
  r[threadIdx.x] = s;
  __syncthreads();
  for (int off = 128; off > 0; off >>= 1) {
    if ((int)threadIdx.x < off) r[threadIdx.x] += r[threadIdx.x + off];
    __syncthreads();
  }
  if (threadIdx.x == 0) gadd(&pooled[bid], r[0] * (1.0f / (float)HWdim));
}

__global__ __launch_bounds__(128) void k_mlp(
    const float* __restrict__ pooled,
    const float* __restrict__ w1b, const float* __restrict__ b1b,
    const float* __restrict__ w2b, const float* __restrict__ b2b,
    const float* __restrict__ w1t, const float* __restrict__ b1t,
    const float* __restrict__ w2t, const float* __restrict__ b2t,
    float* __restrict__ wt)
{
  __shared__ float hdn[Bdim][4];
  __shared__ float lg[Bdim][48];
  int t = threadIdx.x;
  for (int br = 0; br < 2; ++br) {
    const float* w1 = br ? w1t : w1b;
    const float* b1 = br ? b1t : b1b;
    const float* w2 = br ? w2t : w2b;
    const float* b2 = br ? b2t : b2b;
    if (t < 8) {
      int b = t >> 2, h = t & 3;
      float s = b1[h];
      for (int c = 0; c < C_CH; ++c) s += pooled[br * 32 + b * 16 + c] * w1[h * 16 + c];
      hdn[b][h] = fmaxf(s, 0.f);
    }
    __syncthreads();
    if (t < 96) {
      int b = t / 48, j = t - b * 48;
      float s = b2[j];
      for (int h = 0; h < 4; ++h) s += hdn[b][h] * w2[j * 4 + h];
      lg[b][j] = s;
    }
    __syncthreads();
    if (t < 32) {
      int b = t >> 4, c = t & 15;
      float l0 = lg[b][c], l1 = lg[b][16 + c], l2 = lg[b][32 + c];
      float m = fmaxf(l0, fmaxf(l1, l2));
      float e0 = __expf(l0 - m), e1 = __expf(l1 - m), e2 = __expf(l2 - m);
      float inv = 1.f / (e0 + e1 + e2);
      wt[((br * 2 + b) * 3 + 0) * 16 + c] = e0 * inv;
      wt[((br * 2 + b) * 3 + 1) * 16 + c] = e1 * inv;
      wt[((br * 2 + b) * 3 + 2) * 16 + c] = e2 * inv;
    }
    __syncthreads();
  }
}

__global__ __launch_bounds__(256) void k_out(const float* __restrict__ feats,
                                             const float* __restrict__ wt,
                                             float* __restrict__ out)
{
  int idx = blockIdx.x * 256 + threadIdx.x;      // 0 .. 2*PAIR_ELEMS-1
  int br  = idx >> 19;                           // PAIR_ELEMS == 2^19
  int rem = idx & ((1 << 19) - 1);
  int bc  = rem >> 14;
  int b = bc >> 4, c = bc & 15;
  const float* fb = feats + (size_t)br * 3 * PAIR_ELEMS + rem;
  float w0 = wt[((br * 2 + b) * 3 + 0) * 16 + c];
  float w1 = wt[((br * 2 + b) * 3 + 1) * 16 + c];
  float w2 = wt[((br * 2 + b) * 3 + 2) * 16 + c];
  out[idx] = w0 * fb[0] + w1 * fb[PAIR_ELEMS] + w2 * fb[2 * PAIR_ELEMS];
}

// ---------------------------------------------------------------------------
extern "C" void kernel_launch(void* const* d_in, const int* in_sizes, int n_in,
                              void* d_out, int out_size, void* d_ws, size_t ws_size,
                              hipStream_t stream)
{
  const float* bg = (const float*)d_in[0];
  const float* tg = (const float*)d_in[1];
  const float* bg_mem[3]  = {(const float*)d_in[2],  (const float*)d_in[6],  (const float*)d_in[10]};
  const float* tg_mem[3]  = {(const float*)d_in[3],  (const float*)d_in[7],  (const float*)d_in[11]};
  const float* bg_temp[3] = {(const float*)d_in[4],  (const float*)d_in[8],  (const float*)d_in[12]};
  const float* tg_temp[3] = {(const float*)d_in[5],  (const float*)d_in[9],  (const float*)d_in[13]};
  const float* bg_fc1_w = (const float*)d_in[14];
  const float* bg_fc1_b = (const float*)d_in[15];
  const float* bg_fc2_w = (const float*)d_in[16];
  const float* bg_fc2_b = (const float*)d_in[17];
  const float* tg_fc1_w = (const float*)d_in[18];
  const float* tg_fc1_b = (const float*)d_in[19];
  const float* tg_fc2_w = (const float*)d_in[20];
  const float* tg_fc2_b = (const float*)d_in[21];

  float* ws      = (float*)d_ws;
  float* att_bg  = ws;                               // 2*64*16384 = 2097152
  float* att_tg  = att_bg + 2097152;                 // 2*8*16384  = 262144
  float* feats   = att_tg + 262144;                  // 6 * 524288 = 3145728
  float* pooled  = feats + 6 * (size_t)PAIR_ELEMS;   // 64
  float* wt      = pooled + 64;                      // 192
  float* memT    = wt + 192;                         // 95616
  float* memR    = memT + 95616;                     // 95616

  // zero feats + pooled (atomic accumulation targets)
  hipMemsetAsync(feats, 0, (6 * (size_t)PAIR_ELEMS + 64) * sizeof(float), stream);

  const int   Ms[6] = {64, 64, 64, 8, 8, 8};
  const int   Ps[6] = {3, 5, 7, 3, 5, 7};
  const float* mems[6]  = {bg_mem[0], bg_mem[1], bg_mem[2], tg_mem[0], tg_mem[1], tg_mem[2]};
  const float* temps[6] = {bg_temp[0], bg_temp[1], bg_temp[2], tg_temp[0], tg_temp[1], tg_temp[2]};
  float* memTs[6]; float* memRs[6];
  PrepArgs pa;
  size_t off = 0;
  for (int k = 0; k < 6; ++k) {
    int D = C_CH * Ps[k] * Ps[k];
    memTs[k] = memT + off;
    memRs[k] = memR + off;
    pa.d[k] = {mems[k], temps[k], memTs[k], memRs[k], Ms[k], D, Ps[k]};
    off += (size_t)Ms[k] * D;
  }
  k_prep<<<dim3(196, 6), 256, 0, stream>>>(pa);

  dim3 gs(16, 16, 4), bs(512);
  dim3 gr(16, 16, 10), br(256);

  k_sim<3><<<gs, bs, 0, stream>>>(bg, tg, memTs[0], memTs[3], att_bg, att_tg);
  k_read<3><<<gr, br, 0, stream>>>(att_bg, att_tg, memRs[0], memRs[3],
                                   feats + 0 * (size_t)PAIR_ELEMS,
                                   feats + 3 * (size_t)PAIR_ELEMS);
  k_sim<5><<<gs, bs, 0, stream>>>(bg, tg, memTs[1], memTs[4], att_bg, att_tg);
  k_read<5><<<gr, br, 0, stream>>>(att_bg, att_tg, memRs[1], memRs[4],
                                   feats + 1 * (size_t)PAIR_ELEMS,
                                   feats + 4 * (size_t)PAIR_ELEMS);
  k_sim<7><<<gs, bs, 0, stream>>>(bg, tg, memTs[2], memTs[5], att_bg, att_tg);
  k_read<7><<<gr, br, 0, stream>>>(att_bg, att_tg, memRs[2], memRs[5],
                                   feats + 2 * (size_t)PAIR_ELEMS,
                                   feats + 5 * (size_t)PAIR_ELEMS);

  k_pool<<<dim3(64, 4), 256, 0, stream>>>(feats, pooled);
  k_mlp<<<1, 128, 0, stream>>>(pooled, bg_fc1_w, bg_fc1_b, bg_fc2_w, bg_fc2_b,
                               tg_fc1_w, tg_fc1_b, tg_fc2_w, tg_fc2_b, wt);
  k_out<<<(2 * PAIR_ELEMS) / 256, 256, 0, stream>>>(feats, wt, (float*)d_out);
}